// Round 1
// 1506.754 us; speedup vs baseline: 1.2183x; 1.2183x over previous
//
#include <hip/hip_runtime.h>
#include <hip/hip_bf16.h>

// ---------------------------------------------------------------------------
// Fused attention module: Q/K/V proj (bf16 MFMA) + RoPE + causal flash attn
// (bf16 MFMA, fp32 softmax) + output proj (fp32 out).
// MI355X / gfx950. All heavy math via mfma_f32_16x16x32_bf16.
// Verified layouts (learn_hip m89/m91/m120):
//   A-frag: A[m=lane&15][k=(lane>>4)*8+j]
//   B-frag: B[k=(lane>>4)*8+j][n=lane&15]
//   C/D   : col=lane&15, row=(lane>>4)*4+reg
// R1: flash_attn LDS bank-conflict elimination:
//   - Ks[64][128] XOR-swizzled (byte ^ ((row&7)<<4)), staged via
//     global_load_lds with pre-swizzled SOURCE (linear dest — rule #21).
//   - Vt[128][64] XOR-swizzled; V staged key-major across lanes so the
//     transposed scalar writes are wave-contiguous (were 16-way conflicts).
//   - s_setprio(1) around MFMA clusters (T5, attn-proven).
//   - RoPE vectorized bf16x8.
// ---------------------------------------------------------------------------

typedef __bf16 bf16x8 __attribute__((ext_vector_type(8)));
typedef __bf16 bf16x4 __attribute__((ext_vector_type(4)));
typedef float  f32x4  __attribute__((ext_vector_type(4)));

#define GLD_A1(p) ((__attribute__((address_space(1))) void*)(p))
#define GLD_A3(p) ((__attribute__((address_space(3))) void*)(p))

static constexpr int   BATCH = 2;
static constexpr int   TSEQ  = 2048;
static constexpr int   DM    = 4096;
static constexpr int   NH    = 32;
static constexpr int   DH    = 128;
static constexpr size_t TS   = (size_t)DM * DM;   // 16,777,216 elems (== B*T*DM too)

// ---------------------------------------------------------------------------
// fp32 -> bf16 cast, 4 elems/thread
// ---------------------------------------------------------------------------
__global__ __launch_bounds__(256) void cast_f32_bf16(const float* __restrict__ in,
                                                     __bf16* __restrict__ out) {
    size_t id = (size_t)blockIdx.x * blockDim.x + threadIdx.x;
    float4 v = ((const float4*)in)[id];
    bf16x4 o = { (__bf16)v.x, (__bf16)v.y, (__bf16)v.z, (__bf16)v.w };
    *(bf16x4*)(out + id * 4) = o;
}

// ---------------------------------------------------------------------------
// NT GEMM: C[m][n] = sum_k A[m][k] * W[n][k];  M=N=K=4096.
// m97 structure: 128x128 tile, BK=32, 256 thr (4 waves), global_load_lds w=16.
// ---------------------------------------------------------------------------
template <bool OUT_F32>
__global__ __launch_bounds__(256) void gemm_nt(const __bf16* __restrict__ A,
                                               const __bf16* __restrict__ W,
                                               void* __restrict__ Cout) {
    constexpr int Kd = 4096, Nd = 4096;
    __shared__ alignas(16) __bf16 As[128 * 32];
    __shared__ alignas(16) __bf16 Bs[128 * 32];

    const int t = threadIdx.x, w = t >> 6, L = t & 63;
    const int lane15 = L & 15, quad = L >> 4;
    const int rowBlock = blockIdx.y * 128, colBlock = blockIdx.x * 128;
    const int wr = (w >> 1) * 64, wc = (w & 1) * 64;

    f32x4 acc[4][4] = {};

    for (int kb = 0; kb < Kd; kb += 32) {
        __syncthreads();  // prior-iter LDS reads done
#pragma unroll
        for (int i = 0; i < 2; i++) {
            const int chunk = w * 128 + i * 64 + L;     // 0..511, 16B each
            const int row = chunk >> 2, c8 = (chunk & 3) * 8;
            __builtin_amdgcn_global_load_lds(
                GLD_A1(A + (size_t)(rowBlock + row) * Kd + kb + c8),
                GLD_A3(As + (size_t)(w * 128 + i * 64) * 8), 16, 0, 0);
            __builtin_amdgcn_global_load_lds(
                GLD_A1(W + (size_t)(colBlock + row) * Kd + kb + c8),
                GLD_A3(Bs + (size_t)(w * 128 + i * 64) * 8), 16, 0, 0);
        }
        __syncthreads();  // drains vmcnt -> LDS populated

        bf16x8 a[4], b[4];
#pragma unroll
        for (int i = 0; i < 4; i++)
            a[i] = *(const bf16x8*)(As + (wr + i * 16 + lane15) * 32 + quad * 8);
#pragma unroll
        for (int j = 0; j < 4; j++)
            b[j] = *(const bf16x8*)(Bs + (wc + j * 16 + lane15) * 32 + quad * 8);
#pragma unroll
        for (int i = 0; i < 4; i++)
#pragma unroll
            for (int j = 0; j < 4; j++)
                acc[i][j] = __builtin_amdgcn_mfma_f32_16x16x32_bf16(a[i], b[j], acc[i][j], 0, 0, 0);
    }

#pragma unroll
    for (int i = 0; i < 4; i++)
#pragma unroll
        for (int j = 0; j < 4; j++)
#pragma unroll
            for (int r = 0; r < 4; r++) {
                const size_t gm = rowBlock + wr + i * 16 + quad * 4 + r;
                const size_t gn = colBlock + wc + j * 16 + lane15;
                if (OUT_F32)
                    ((float*)Cout)[gm * Nd + gn] = acc[i][j][r];
                else
                    ((__bf16*)Cout)[gm * Nd + gn] = (__bf16)acc[i][j][r];
            }
}

// ---------------------------------------------------------------------------
// RoPE in place on (B*T, 4096) bf16, vectorized: 8 elems (4 pairs) / thread.
// Pair p of head rotates by angle = t * theta^(-((2p)%64)/64), theta=20000.
// ---------------------------------------------------------------------------
__global__ __launch_bounds__(256) void rope_inplace(__bf16* __restrict__ X) {
    const size_t id = (size_t)blockIdx.x * blockDim.x + threadIdx.x;  // one per 8 elems
    const int g = (int)(id & 511);          // 8-elem group within row (4096/8)
    const size_t row = id >> 9;             // 0..4095
    const int tpos = (int)(row & (TSEQ - 1));
    __bf16* p = X + row * DM + (size_t)g * 8;
    bf16x8 v = *(const bf16x8*)p;
    bf16x8 o;
#pragma unroll
    for (int pr = 0; pr < 4; pr++) {
        const int pcol = g * 4 + pr;            // pair index within row, 0..2047
        const int j = (2 * (pcol & 63)) & 63;   // freq index
        // log2(20000) = 14.287712379549449
        const float inv = exp2f(-(float)j * (14.287712379549449f / 64.0f));
        const float ang = (float)tpos * inv;
        float s, c;
        sincosf(ang, &s, &c);
        const float x0 = (float)v[2 * pr], x1 = (float)v[2 * pr + 1];
        o[2 * pr]     = (__bf16)(x0 * c - x1 * s);
        o[2 * pr + 1] = (__bf16)(x0 * s + x1 * c);
    }
    *(bf16x8*)p = o;
}

// ---------------------------------------------------------------------------
// Flash attention, causal. Q,K,V,O all (B*T, 4096) bf16 with head offset h*128.
// Block: 256 thr (4 waves). Q tile 64 rows (16/wave), K/V tiles of 64 keys.
// LDS layouts (all conflict-free, see R1 header):
//   Ks[key][dim]  64x128, 256B rows, 16B slot s stored at s ^ (key&7)
//   Vt[dim][key] 128x64, 128B rows, byte col ^ ((dim&7)<<4)
//   Ps[qrow][key] 64x72 (+8 pad, 2-way at worst)
// ---------------------------------------------------------------------------
__global__ __launch_bounds__(256) void flash_attn(const __bf16* __restrict__ Qg,
                                                  const __bf16* __restrict__ Kg,
                                                  const __bf16* __restrict__ Vg,
                                                  __bf16* __restrict__ Og) {
    const int qb = blockIdx.x;           // 0..31 (q tile)
    const int bh = blockIdx.y;           // 0..63
    const int b = bh >> 5, h = bh & 31;
    const size_t base = (size_t)b * TSEQ * DM + (size_t)h * DH;
    const __bf16* Qp = Qg + base;
    const __bf16* Kp = Kg + base;
    const __bf16* Vp = Vg + base;
    __bf16*       Op = Og + base;

    __shared__ alignas(16) __bf16 Ks[64 * 128];
    __shared__ alignas(16) __bf16 Vt[128 * 64];
    __shared__ alignas(16) __bf16 Ps[64 * 72];

    const int t = threadIdx.x, w = t >> 6, L = t & 63;
    const int lane15 = L & 15, quad = L >> 4;
    const int sw = (lane15 & 7) << 4;    // read-side XOR: row&7 == lane15&7 for both Ks,Vt

    // Q A-frags live in registers for the whole block (16 rows per wave).
    bf16x8 aq[4];
    {
        const int qrow = qb * 64 + w * 16 + lane15;
#pragma unroll
        for (int ks = 0; ks < 4; ++ks)
            aq[ks] = *(const bf16x8*)(Qp + (size_t)qrow * DM + ks * 32 + quad * 8);
    }

    f32x4 o[8] = {};
    float m_i[4], l_i[4];
#pragma unroll
    for (int r = 0; r < 4; r++) { m_i[r] = -1e30f; l_i[r] = 0.0f; }
    const float scale = 0.08838834764831845f;  // 1/sqrt(128)

    for (int kt = 0; kt <= qb; ++kt) {
        // ---- stage V (reg) : lane -> key, wave -> dim-blocks ----
        bf16x8 vv[4];
#pragma unroll
        for (int c = 0; c < 4; c++) {
            const int d0 = (c * 4 + w) * 8;                       // dim block base
            vv[c] = *(const bf16x8*)(Vp + (size_t)(kt * 64 + L) * DM + d0);
        }
        // ---- stage K via global_load_lds, source pre-swizzled ----
#pragma unroll
        for (int c = 0; c < 4; c++) {
            const int chunk0 = c * 256 + (w << 6);                // wave-uniform
            const int chunk  = chunk0 + L;
            const int row = chunk >> 4;                           // key 0..63
            const int ssw = (chunk & 15) ^ (row & 7);             // swizzled source slot
            __builtin_amdgcn_global_load_lds(
                GLD_A1(Kp + (size_t)(kt * 64 + row) * DM + ssw * 8),
                GLD_A3((char*)Ks + chunk0 * 16), 16, 0, 0);
        }
        // ---- transposed V writes: contiguous across 64 lanes, uniform XOR ----
#pragma unroll
        for (int c = 0; c < 4; c++) {
            const int d0 = (c * 4 + w) * 8;
#pragma unroll
            for (int jj = 0; jj < 8; jj++)
                *(__bf16*)((char*)Vt + (d0 + jj) * 128 + ((L * 2) ^ (jj << 4))) = vv[c][jj];
        }
        __syncthreads();

        // ---- S = Q K^T (per wave: 16 rows x 64 keys) ----
        f32x4 s[4] = {};
        __builtin_amdgcn_s_setprio(1);
#pragma unroll
        for (int ks = 0; ks < 4; ++ks)
#pragma unroll
            for (int n = 0; n < 4; n++) {
                bf16x8 bk = *(const bf16x8*)((const char*)Ks + (n * 16 + lane15) * 256
                                             + ((ks * 64 + quad * 16) ^ sw));
                s[n] = __builtin_amdgcn_mfma_f32_16x16x32_bf16(aq[ks], bk, s[n], 0, 0, 0);
            }
        __builtin_amdgcn_s_setprio(0);

        // ---- scale + causal mask ----
        const bool diag = (kt == qb);
#pragma unroll
        for (int n = 0; n < 4; n++) {
            const int col = kt * 64 + n * 16 + lane15;
#pragma unroll
            for (int r = 0; r < 4; r++) {
                const int rowq = qb * 64 + w * 16 + quad * 4 + r;
                float sv = s[n][r] * scale;
                if (diag && col > rowq) sv = -1e30f;
                s[n][r] = sv;
            }
        }

        // ---- online softmax ----
        float mx[4], al[4], rs[4];
#pragma unroll
        for (int r = 0; r < 4; r++)
            mx[r] = fmaxf(fmaxf(s[0][r], s[1][r]), fmaxf(s[2][r], s[3][r]));
#pragma unroll
        for (int off = 8; off >= 1; off >>= 1)
#pragma unroll
            for (int r = 0; r < 4; r++)
                mx[r] = fmaxf(mx[r], __shfl_xor(mx[r], off));
#pragma unroll
        for (int r = 0; r < 4; r++) {
            const float mn = fmaxf(m_i[r], mx[r]);
            al[r] = __expf(m_i[r] - mn);
            m_i[r] = mn;
            rs[r] = 0.0f;
        }
#pragma unroll
        for (int n = 0; n < 4; n++)
#pragma unroll
            for (int r = 0; r < 4; r++) {
                const float p = __expf(s[n][r] - m_i[r]);
                rs[r] += p;
                Ps[(w * 16 + quad * 4 + r) * 72 + n * 16 + lane15] = (__bf16)p;
            }
#pragma unroll
        for (int off = 8; off >= 1; off >>= 1)
#pragma unroll
            for (int r = 0; r < 4; r++)
                rs[r] += __shfl_xor(rs[r], off);
#pragma unroll
        for (int r = 0; r < 4; r++) l_i[r] = l_i[r] * al[r] + rs[r];
#pragma unroll
        for (int d = 0; d < 8; ++d)
#pragma unroll
            for (int r = 0; r < 4; r++) o[d][r] *= al[r];

        __syncthreads();  // P visible (C-layout -> A-layout round trip)

        // ---- O += P V ----
        __builtin_amdgcn_s_setprio(1);
#pragma unroll
        for (int ks2 = 0; ks2 < 2; ++ks2) {
            bf16x8 ap = *(const bf16x8*)(Ps + (w * 16 + lane15) * 72 + ks2 * 32 + quad * 8);
#pragma unroll
            for (int d = 0; d < 8; ++d) {
                bf16x8 bv = *(const bf16x8*)((const char*)Vt + (d * 16 + lane15) * 128
                                             + ((ks2 * 64 + quad * 16) ^ sw));
                o[d] = __builtin_amdgcn_mfma_f32_16x16x32_bf16(ap, bv, o[d], 0, 0, 0);
            }
        }
        __builtin_amdgcn_s_setprio(0);
        __syncthreads();  // before next tile overwrites Ks/Vt
    }

    // ---- epilogue: O / l ----
    float inv_l[4];
#pragma unroll
    for (int r = 0; r < 4; r++) inv_l[r] = 1.0f / l_i[r];
#pragma unroll
    for (int d = 0; d < 8; ++d)
#pragma unroll
        for (int r = 0; r < 4; r++) {
            const int rowq = qb * 64 + w * 16 + quad * 4 + r;
            Op[(size_t)rowq * DM + d * 16 + lane15] = (__bf16)(o[d][r] * inv_l[r]);
        }
}

// ---------------------------------------------------------------------------
extern "C" void kernel_launch(void* const* d_in, const int* in_sizes, int n_in,
                              void* d_out, int out_size, void* d_ws, size_t ws_size,
                              hipStream_t stream) {
    const float* hs = (const float*)d_in[0];
    const float* Wq = (const float*)d_in[1];
    const float* Wk = (const float*)d_in[2];
    const float* Wv = (const float*)d_in[3];
    const float* Wo = (const float*)d_in[4];
    float* out = (float*)d_out;

    // workspace layout: 9 bf16 buffers of TS elems (~302 MB total)
    __bf16* hs_b = (__bf16*)d_ws;
    __bf16* wq_b = hs_b + TS;
    __bf16* wk_b = wq_b + TS;
    __bf16* wv_b = wk_b + TS;
    __bf16* wo_b = wv_b + TS;
    __bf16* Qb   = wo_b + TS;
    __bf16* Kb   = Qb + TS;
    __bf16* Vb   = Kb + TS;
    __bf16* Ab   = Vb + TS;
    if (ws_size < 9 * TS * sizeof(__bf16)) return;  // insufficient scratch

    const dim3 blk(256);
    const int castGrid = (int)(TS / 4 / 256);   // 16384
    cast_f32_bf16<<<castGrid, blk, 0, stream>>>(hs, hs_b);
    cast_f32_bf16<<<castGrid, blk, 0, stream>>>(Wq, wq_b);
    cast_f32_bf16<<<castGrid, blk, 0, stream>>>(Wk, wk_b);
    cast_f32_bf16<<<castGrid, blk, 0, stream>>>(Wv, wv_b);
    cast_f32_bf16<<<castGrid, blk, 0, stream>>>(Wo, wo_b);

    const dim3 ggrid(32, 32);  // (N/128, M/128)
    gemm_nt<false><<<ggrid, blk, 0, stream>>>(hs_b, wq_b, (void*)Qb);
    gemm_nt<false><<<ggrid, blk, 0, stream>>>(hs_b, wk_b, (void*)Kb);
    gemm_nt<false><<<ggrid, blk, 0, stream>>>(hs_b, wv_b, (void*)Vb);

    const int ropeGrid = (int)(TS / 8 / 256);   // 8192
    rope_inplace<<<ropeGrid, blk, 0, stream>>>(Qb);
    rope_inplace<<<ropeGrid, blk, 0, stream>>>(Kb);

    flash_attn<<<dim3(32, 64), blk, 0, stream>>>(Qb, Kb, Vb, Ab);

    gemm_nt<true><<<ggrid, blk, 0, stream>>>(Ab, wo_b, (void*)out);
}

// Round 2
// 1486.741 us; speedup vs baseline: 1.2347x; 1.0135x over previous
//
#include <hip/hip_runtime.h>
#include <hip/hip_bf16.h>

// ---------------------------------------------------------------------------
// Fused attention module: Q/K/V proj (bf16 MFMA) + RoPE + causal flash attn
// (bf16 MFMA, fp32 softmax) + output proj (fp32 out).
// MI355X / gfx950. All heavy math via mfma_f32_16x16x32_bf16.
// Verified layouts (learn_hip m89/m91/m120):
//   A-frag: A[m=lane&15][k=(lane>>4)*8+j]
//   B-frag: B[k=(lane>>4)*8+j][n=lane&15]
//   C/D   : col=lane&15, row=(lane>>4)*4+reg
// R1: LDS bank-conflict elimination (conflicts 1.48e8 -> 9.7e6, 745->420us).
// R2: latency pipeline: Ks double-buffered + K/V prefetch issued at top of
//     iter (T14 issue-early/write-late for V), raw lgkm-only mid barriers
//     (no vmcnt drain -> prefetch stays in flight), ONE full drain per iter.
//     Heavy-first block order for the triangular-work tail. Merged cast/rope
//     launches.
// ---------------------------------------------------------------------------

typedef __bf16 bf16x8 __attribute__((ext_vector_type(8)));
typedef __bf16 bf16x4 __attribute__((ext_vector_type(4)));
typedef float  f32x4  __attribute__((ext_vector_type(4)));

#define GLD_A1(p) ((__attribute__((address_space(1))) void*)(p))
#define GLD_A3(p) ((__attribute__((address_space(3))) void*)(p))

static constexpr int   BATCH = 2;
static constexpr int   TSEQ  = 2048;
static constexpr int   DM    = 4096;
static constexpr int   NH    = 32;
static constexpr int   DH    = 128;
static constexpr size_t TS   = (size_t)DM * DM;   // 16,777,216 elems (== B*T*DM too)

// ---------------------------------------------------------------------------
// fp32 -> bf16 cast, 4 elems/thread. grid.y selects source (dests contiguous).
// ---------------------------------------------------------------------------
__global__ __launch_bounds__(256) void cast5_f32_bf16(const float* __restrict__ s0,
                                                      const float* __restrict__ s1,
                                                      const float* __restrict__ s2,
                                                      const float* __restrict__ s3,
                                                      const float* __restrict__ s4,
                                                      __bf16* __restrict__ out) {
    const int which = blockIdx.y;
    const float* s = which == 0 ? s0 : which == 1 ? s1 : which == 2 ? s2
                   : which == 3 ? s3 : s4;
    size_t id = (size_t)blockIdx.x * blockDim.x + threadIdx.x;
    float4 v = ((const float4*)s)[id];
    bf16x4 o = { (__bf16)v.x, (__bf16)v.y, (__bf16)v.z, (__bf16)v.w };
    *(bf16x4*)(out + (size_t)which * TS + id * 4) = o;
}

// ---------------------------------------------------------------------------
// NT GEMM: C[m][n] = sum_k A[m][k] * W[n][k];  M=N=K=4096.
// m97 structure: 128x128 tile, BK=32, 256 thr (4 waves), global_load_lds w=16.
// ---------------------------------------------------------------------------
template <bool OUT_F32>
__global__ __launch_bounds__(256) void gemm_nt(const __bf16* __restrict__ A,
                                               const __bf16* __restrict__ W,
                                               void* __restrict__ Cout) {
    constexpr int Kd = 4096, Nd = 4096;
    __shared__ alignas(16) __bf16 As[128 * 32];
    __shared__ alignas(16) __bf16 Bs[128 * 32];

    const int t = threadIdx.x, w = t >> 6, L = t & 63;
    const int lane15 = L & 15, quad = L >> 4;
    const int rowBlock = blockIdx.y * 128, colBlock = blockIdx.x * 128;
    const int wr = (w >> 1) * 64, wc = (w & 1) * 64;

    f32x4 acc[4][4] = {};

    for (int kb = 0; kb < Kd; kb += 32) {
        __syncthreads();  // prior-iter LDS reads done
#pragma unroll
        for (int i = 0; i < 2; i++) {
            const int chunk = w * 128 + i * 64 + L;     // 0..511, 16B each
            const int row = chunk >> 2, c8 = (chunk & 3) * 8;
            __builtin_amdgcn_global_load_lds(
                GLD_A1(A + (size_t)(rowBlock + row) * Kd + kb + c8),
                GLD_A3(As + (size_t)(w * 128 + i * 64) * 8), 16, 0, 0);
            __builtin_amdgcn_global_load_lds(
                GLD_A1(W + (size_t)(colBlock + row) * Kd + kb + c8),
                GLD_A3(Bs + (size_t)(w * 128 + i * 64) * 8), 16, 0, 0);
        }
        __syncthreads();  // drains vmcnt -> LDS populated

        bf16x8 a[4], b[4];
#pragma unroll
        for (int i = 0; i < 4; i++)
            a[i] = *(const bf16x8*)(As + (wr + i * 16 + lane15) * 32 + quad * 8);
#pragma unroll
        for (int j = 0; j < 4; j++)
            b[j] = *(const bf16x8*)(Bs + (wc + j * 16 + lane15) * 32 + quad * 8);
#pragma unroll
        for (int i = 0; i < 4; i++)
#pragma unroll
            for (int j = 0; j < 4; j++)
                acc[i][j] = __builtin_amdgcn_mfma_f32_16x16x32_bf16(a[i], b[j], acc[i][j], 0, 0, 0);
    }

#pragma unroll
    for (int i = 0; i < 4; i++)
#pragma unroll
        for (int j = 0; j < 4; j++)
#pragma unroll
            for (int r = 0; r < 4; r++) {
                const size_t gm = rowBlock + wr + i * 16 + quad * 4 + r;
                const size_t gn = colBlock + wc + j * 16 + lane15;
                if (OUT_F32)
                    ((float*)Cout)[gm * Nd + gn] = acc[i][j][r];
                else
                    ((__bf16*)Cout)[gm * Nd + gn] = (__bf16)acc[i][j][r];
            }
}

// ---------------------------------------------------------------------------
// RoPE in place on (B*T, 4096) bf16, vectorized: 8 elems (4 pairs) / thread.
// grid.y: 0 -> Q buffer, 1 -> K buffer.
// ---------------------------------------------------------------------------
__global__ __launch_bounds__(256) void rope2_inplace(__bf16* __restrict__ Q,
                                                     __bf16* __restrict__ K) {
    __bf16* X = blockIdx.y == 0 ? Q : K;
    const size_t id = (size_t)blockIdx.x * blockDim.x + threadIdx.x;  // one per 8 elems
    const int g = (int)(id & 511);          // 8-elem group within row (4096/8)
    const size_t row = id >> 9;             // 0..4095
    const int tpos = (int)(row & (TSEQ - 1));
    __bf16* p = X + row * DM + (size_t)g * 8;
    bf16x8 v = *(const bf16x8*)p;
    bf16x8 o;
#pragma unroll
    for (int pr = 0; pr < 4; pr++) {
        const int pcol = g * 4 + pr;            // pair index within row, 0..2047
        const int j = (2 * (pcol & 63)) & 63;   // freq index
        // log2(20000) = 14.287712379549449
        const float inv = exp2f(-(float)j * (14.287712379549449f / 64.0f));
        const float ang = (float)tpos * inv;
        float s, c;
        sincosf(ang, &s, &c);
        const float x0 = (float)v[2 * pr], x1 = (float)v[2 * pr + 1];
        o[2 * pr]     = (__bf16)(x0 * c - x1 * s);
        o[2 * pr + 1] = (__bf16)(x0 * s + x1 * c);
    }
    *(bf16x8*)p = o;
}

// ---------------------------------------------------------------------------
// Flash attention, causal. Q,K,V,O all (B*T, 4096) bf16 with head offset h*128.
// Block: 256 thr (4 waves). Q tile 64 rows (16/wave), K/V tiles of 64 keys.
// LDS layouts (conflict-free, see R1):
//   Ks[2][key][dim] 64x128, 256B rows, 16B slot s stored at s ^ (key&7) [dbuf]
//   Vt[dim][key]   128x64, 128B rows, byte col ^ ((dim&7)<<4)  [single]
//   Ps[qrow][key]   64x72 (+8 pad, ~2-way residual)
// Pipeline per iter t (R2):
//   issue V[t+1]->regs, K[t+1]->Ks[nxt] (gload_lds)         } in flight
//   QK^T(Ks[cur]) ; softmax -> Ps                           } across raw
//   raw barrier (lgkm only)                                 } barriers
//   PV(Ps, Vt)                                              }
//   raw barrier ; Vt <= vv (write-late)                     }
//   __syncthreads (single vmcnt drain per iter)
// ---------------------------------------------------------------------------
__global__ __launch_bounds__(256) void flash_attn(const __bf16* __restrict__ Qg,
                                                  const __bf16* __restrict__ Kg,
                                                  const __bf16* __restrict__ Vg,
                                                  __bf16* __restrict__ Og) {
    const int qb = 31 - blockIdx.x;      // heavy-first: big qb dispatched first
    const int bh = blockIdx.y;           // 0..63
    const int b = bh >> 5, h = bh & 31;
    const size_t base = (size_t)b * TSEQ * DM + (size_t)h * DH;
    const __bf16* Qp = Qg + base;
    const __bf16* Kp = Kg + base;
    const __bf16* Vp = Vg + base;
    __bf16*       Op = Og + base;

    __shared__ alignas(16) __bf16 Ks[2][64 * 128];
    __shared__ alignas(16) __bf16 Vt[128 * 64];
    __shared__ alignas(16) __bf16 Ps[64 * 72];

    const int t = threadIdx.x, w = t >> 6, L = t & 63;
    const int lane15 = L & 15, quad = L >> 4;
    const int sw = (lane15 & 7) << 4;    // read-side XOR: row&7 == lane15&7 for both Ks,Vt

    // Q A-frags live in registers for the whole block (16 rows per wave).
    bf16x8 aq[4];
    {
        const int qrow = qb * 64 + w * 16 + lane15;
#pragma unroll
        for (int ks = 0; ks < 4; ++ks)
            aq[ks] = *(const bf16x8*)(Qp + (size_t)qrow * DM + ks * 32 + quad * 8);
    }

    f32x4 o[8] = {};
    float m_i[4], l_i[4];
#pragma unroll
    for (int r = 0; r < 4; r++) { m_i[r] = -1e30f; l_i[r] = 0.0f; }
    const float scale = 0.08838834764831845f;  // 1/sqrt(128)

    // ---- prologue: stage tile 0 (V->regs->Vt, K->Ks[0]) ----
    {
        bf16x8 v0[4];
#pragma unroll
        for (int c = 0; c < 4; c++) {
            const int d0 = (c * 4 + w) * 8;
            v0[c] = *(const bf16x8*)(Vp + (size_t)L * DM + d0);
        }
#pragma unroll
        for (int c = 0; c < 4; c++) {
            const int chunk0 = c * 256 + (w << 6);                // wave-uniform
            const int chunk  = chunk0 + L;
            const int row = chunk >> 4;                           // key 0..63
            const int ssw = (chunk & 15) ^ (row & 7);             // pre-swizzled source
            __builtin_amdgcn_global_load_lds(
                GLD_A1(Kp + (size_t)row * DM + ssw * 8),
                GLD_A3((char*)Ks[0] + chunk0 * 16), 16, 0, 0);
        }
#pragma unroll
        for (int c = 0; c < 4; c++) {
            const int d0 = (c * 4 + w) * 8;
#pragma unroll
            for (int jj = 0; jj < 8; jj++)
                *(__bf16*)((char*)Vt + (d0 + jj) * 128 + ((L * 2) ^ (jj << 4))) = v0[c][jj];
        }
    }
    __syncthreads();

    int cur = 0;
    for (int kt = 0; kt <= qb; ++kt) {
        const int nxt = cur ^ 1;
        const bool pf = (kt < qb);       // block-uniform

        // ---- prefetch tile kt+1: V -> regs (consumed write-late), K -> Ks[nxt]
        bf16x8 vv[4];
        if (pf) {
#pragma unroll
            for (int c = 0; c < 4; c++) {
                const int d0 = (c * 4 + w) * 8;
                vv[c] = *(const bf16x8*)(Vp + (size_t)((kt + 1) * 64 + L) * DM + d0);
            }
#pragma unroll
            for (int c = 0; c < 4; c++) {
                const int chunk0 = c * 256 + (w << 6);
                const int chunk  = chunk0 + L;
                const int row = chunk >> 4;
                const int ssw = (chunk & 15) ^ (row & 7);
                __builtin_amdgcn_global_load_lds(
                    GLD_A1(Kp + (size_t)((kt + 1) * 64 + row) * DM + ssw * 8),
                    GLD_A3((char*)Ks[nxt] + chunk0 * 16), 16, 0, 0);
            }
        }

        // ---- S = Q K^T (per wave: 16 rows x 64 keys) ----
        f32x4 s[4] = {};
        __builtin_amdgcn_s_setprio(1);
#pragma unroll
        for (int ks = 0; ks < 4; ++ks)
#pragma unroll
            for (int n = 0; n < 4; n++) {
                bf16x8 bk = *(const bf16x8*)((const char*)Ks[cur] + (n * 16 + lane15) * 256
                                             + ((ks * 64 + quad * 16) ^ sw));
                s[n] = __builtin_amdgcn_mfma_f32_16x16x32_bf16(aq[ks], bk, s[n], 0, 0, 0);
            }
        __builtin_amdgcn_s_setprio(0);

        // ---- scale + causal mask ----
        const bool diag = (kt == qb);
#pragma unroll
        for (int n = 0; n < 4; n++) {
            const int col = kt * 64 + n * 16 + lane15;
#pragma unroll
            for (int r = 0; r < 4; r++) {
                const int rowq = qb * 64 + w * 16 + quad * 4 + r;
                float sv = s[n][r] * scale;
                if (diag && col > rowq) sv = -1e30f;
                s[n][r] = sv;
            }
        }

        // ---- online softmax ----
        float mx[4], al[4], rs[4];
#pragma unroll
        for (int r = 0; r < 4; r++)
            mx[r] = fmaxf(fmaxf(s[0][r], s[1][r]), fmaxf(s[2][r], s[3][r]));
#pragma unroll
        for (int off = 8; off >= 1; off >>= 1)
#pragma unroll
            for (int r = 0; r < 4; r++)
                mx[r] = fmaxf(mx[r], __shfl_xor(mx[r], off));
#pragma unroll
        for (int r = 0; r < 4; r++) {
            const float mn = fmaxf(m_i[r], mx[r]);
            al[r] = __expf(m_i[r] - mn);
            m_i[r] = mn;
            rs[r] = 0.0f;
        }
#pragma unroll
        for (int n = 0; n < 4; n++)
#pragma unroll
            for (int r = 0; r < 4; r++) {
                const float p = __expf(s[n][r] - m_i[r]);
                rs[r] += p;
                Ps[(w * 16 + quad * 4 + r) * 72 + n * 16 + lane15] = (__bf16)p;
            }
#pragma unroll
        for (int off = 8; off >= 1; off >>= 1)
#pragma unroll
            for (int r = 0; r < 4; r++)
                rs[r] += __shfl_xor(rs[r], off);
#pragma unroll
        for (int r = 0; r < 4; r++) l_i[r] = l_i[r] * al[r] + rs[r];
#pragma unroll
        for (int d = 0; d < 8; ++d)
#pragma unroll
            for (int r = 0; r < 4; r++) o[d][r] *= al[r];

        // Ps visible; lgkm-only wait so prefetch (vmcnt) stays in flight.
        asm volatile("s_waitcnt lgkmcnt(0)\n\ts_barrier" ::: "memory");

        // ---- O += P V ----
        __builtin_amdgcn_s_setprio(1);
#pragma unroll
        for (int ks2 = 0; ks2 < 2; ++ks2) {
            bf16x8 ap = *(const bf16x8*)(Ps + (w * 16 + lane15) * 72 + ks2 * 32 + quad * 8);
#pragma unroll
            for (int d = 0; d < 8; ++d) {
                bf16x8 bv = *(const bf16x8*)((const char*)Vt + (d * 16 + lane15) * 128
                                             + ((ks2 * 64 + quad * 16) ^ sw));
                o[d] = __builtin_amdgcn_mfma_f32_16x16x32_bf16(ap, bv, o[d], 0, 0, 0);
            }
        }
        __builtin_amdgcn_s_setprio(0);

        // All waves done reading Vt (own ds ops retired via lgkm wait) ->
        // safe to overwrite. vmcnt not drained here.
        asm volatile("s_waitcnt lgkmcnt(0)\n\ts_barrier" ::: "memory");

        if (pf) {
#pragma unroll
            for (int c = 0; c < 4; c++) {
                const int d0 = (c * 4 + w) * 8;
#pragma unroll
                for (int jj = 0; jj < 8; jj++)
                    *(__bf16*)((char*)Vt + (d0 + jj) * 128 + ((L * 2) ^ (jj << 4))) = vv[c][jj];
            }
        }
        __syncthreads();  // single full drain: Ks[nxt] gload_lds + Vt writes
        cur = nxt;
    }

    // ---- epilogue: O / l ----
    float inv_l[4];
#pragma unroll
    for (int r = 0; r < 4; r++) inv_l[r] = 1.0f / l_i[r];
#pragma unroll
    for (int d = 0; d < 8; ++d)
#pragma unroll
        for (int r = 0; r < 4; r++) {
            const int rowq = qb * 64 + w * 16 + quad * 4 + r;
            Op[(size_t)rowq * DM + d * 16 + lane15] = (__bf16)(o[d][r] * inv_l[r]);
        }
}

// ---------------------------------------------------------------------------
extern "C" void kernel_launch(void* const* d_in, const int* in_sizes, int n_in,
                              void* d_out, int out_size, void* d_ws, size_t ws_size,
                              hipStream_t stream) {
    const float* hs = (const float*)d_in[0];
    const float* Wq = (const float*)d_in[1];
    const float* Wk = (const float*)d_in[2];
    const float* Wv = (const float*)d_in[3];
    const float* Wo = (const float*)d_in[4];
    float* out = (float*)d_out;

    // workspace layout: 9 bf16 buffers of TS elems (~302 MB total)
    __bf16* hs_b = (__bf16*)d_ws;
    __bf16* wq_b = hs_b + TS;
    __bf16* wk_b = wq_b + TS;
    __bf16* wv_b = wk_b + TS;
    __bf16* wo_b = wv_b + TS;
    __bf16* Qb   = wo_b + TS;
    __bf16* Kb   = Qb + TS;
    __bf16* Vb   = Kb + TS;
    __bf16* Ab   = Vb + TS;
    if (ws_size < 9 * TS * sizeof(__bf16)) return;  // insufficient scratch

    const dim3 blk(256);
    // merged cast: grid.y picks source; dests are contiguous from hs_b
    cast5_f32_bf16<<<dim3(TS / 4 / 256, 5), blk, 0, stream>>>(hs, Wq, Wk, Wv, Wo, hs_b);

    const dim3 ggrid(32, 32);  // (N/128, M/128)
    gemm_nt<false><<<ggrid, blk, 0, stream>>>(hs_b, wq_b, (void*)Qb);
    gemm_nt<false><<<ggrid, blk, 0, stream>>>(hs_b, wk_b, (void*)Kb);
    gemm_nt<false><<<ggrid, blk, 0, stream>>>(hs_b, wv_b, (void*)Vb);

    rope2_inplace<<<dim3(TS / 8 / 256, 2), blk, 0, stream>>>(Qb, Kb);

    flash_attn<<<dim3(32, 64), blk, 0, stream>>>(Qb, Kb, Vb, Ab);

    gemm_nt<true><<<ggrid, blk, 0, stream>>>(Ab, wo_b, (void*)out);
}

// Round 4
// 1360.877 us; speedup vs baseline: 1.3489x; 1.0925x over previous
//
#include <hip/hip_runtime.h>
#include <hip/hip_bf16.h>

// ---------------------------------------------------------------------------
// Fused attention module: Q/K/V proj (bf16 MFMA) + RoPE + causal flash attn
// (bf16 MFMA, fp32 softmax) + output proj (fp32 out).
// MI355X / gfx950. All heavy math via mfma_f32_16x16x32_bf16.
// Verified layouts (learn_hip m89/m91/m120):
//   A-frag: A[m=lane&15][k=(lane>>4)*8+j]
//   B-frag: B[k=(lane>>4)*8+j][n=lane&15]
//   C/D   : col=lane&15, row=(lane>>4)*4+reg
// R1: LDS bank-conflict elimination (conflicts 1.48e8 -> 9.7e6, 745->420us).
// R2: latency pipelining -- NEUTRAL (418us): bottleneck is LDS/VALU op count,
//     not latency. Reverted dbuf.
// R3: swapped QK^T (s = mfma(K,Q)) -> softmax row is lane-local:
//     - reduce shuffles 32 -> 4 (in-reg tree + xor16/xor32)
//     - P written as packed bf16x2 to XOR-swizzled Ps[64][64]; round trip is
//       intra-wave -> lgkmcnt wait instead of a barrier (2 barriers/tile)
//     - LDS 40KB -> 4 blocks/CU
// R4: resubmit of R3 (container infra failure; kernel audited OOB/hang-clean).
// ---------------------------------------------------------------------------

typedef __bf16 bf16x8 __attribute__((ext_vector_type(8)));
typedef __bf16 bf16x4 __attribute__((ext_vector_type(4)));
typedef __bf16 bf16x2 __attribute__((ext_vector_type(2)));
typedef float  f32x4  __attribute__((ext_vector_type(4)));

#define GLD_A1(p) ((__attribute__((address_space(1))) void*)(p))
#define GLD_A3(p) ((__attribute__((address_space(3))) void*)(p))

static constexpr int   BATCH = 2;
static constexpr int   TSEQ  = 2048;
static constexpr int   DM    = 4096;
static constexpr int   NH    = 32;
static constexpr int   DH    = 128;
static constexpr size_t TS   = (size_t)DM * DM;   // 16,777,216 elems (== B*T*DM too)

// ---------------------------------------------------------------------------
// fp32 -> bf16 cast, 4 elems/thread. grid.y selects source (dests contiguous).
// ---------------------------------------------------------------------------
__global__ __launch_bounds__(256) void cast5_f32_bf16(const float* __restrict__ s0,
                                                      const float* __restrict__ s1,
                                                      const float* __restrict__ s2,
                                                      const float* __restrict__ s3,
                                                      const float* __restrict__ s4,
                                                      __bf16* __restrict__ out) {
    const int which = blockIdx.y;
    const float* s = which == 0 ? s0 : which == 1 ? s1 : which == 2 ? s2
                   : which == 3 ? s3 : s4;
    size_t id = (size_t)blockIdx.x * blockDim.x + threadIdx.x;
    float4 v = ((const float4*)s)[id];
    bf16x4 o = { (__bf16)v.x, (__bf16)v.y, (__bf16)v.z, (__bf16)v.w };
    *(bf16x4*)(out + (size_t)which * TS + id * 4) = o;
}

// ---------------------------------------------------------------------------
// NT GEMM: C[m][n] = sum_k A[m][k] * W[n][k];  M=N=K=4096.
// m97 structure: 128x128 tile, BK=32, 256 thr (4 waves), global_load_lds w=16.
// ---------------------------------------------------------------------------
template <bool OUT_F32>
__global__ __launch_bounds__(256) void gemm_nt(const __bf16* __restrict__ A,
                                               const __bf16* __restrict__ W,
                                               void* __restrict__ Cout) {
    constexpr int Kd = 4096, Nd = 4096;
    __shared__ alignas(16) __bf16 As[128 * 32];
    __shared__ alignas(16) __bf16 Bs[128 * 32];

    const int t = threadIdx.x, w = t >> 6, L = t & 63;
    const int lane15 = L & 15, quad = L >> 4;
    const int rowBlock = blockIdx.y * 128, colBlock = blockIdx.x * 128;
    const int wr = (w >> 1) * 64, wc = (w & 1) * 64;

    f32x4 acc[4][4] = {};

    for (int kb = 0; kb < Kd; kb += 32) {
        __syncthreads();  // prior-iter LDS reads done
#pragma unroll
        for (int i = 0; i < 2; i++) {
            const int chunk = w * 128 + i * 64 + L;     // 0..511, 16B each
            const int row = chunk >> 2, c8 = (chunk & 3) * 8;
            __builtin_amdgcn_global_load_lds(
                GLD_A1(A + (size_t)(rowBlock + row) * Kd + kb + c8),
                GLD_A3(As + (size_t)(w * 128 + i * 64) * 8), 16, 0, 0);
            __builtin_amdgcn_global_load_lds(
                GLD_A1(W + (size_t)(colBlock + row) * Kd + kb + c8),
                GLD_A3(Bs + (size_t)(w * 128 + i * 64) * 8), 16, 0, 0);
        }
        __syncthreads();  // drains vmcnt -> LDS populated

        bf16x8 a[4], b[4];
#pragma unroll
        for (int i = 0; i < 4; i++)
            a[i] = *(const bf16x8*)(As + (wr + i * 16 + lane15) * 32 + quad * 8);
#pragma unroll
        for (int j = 0; j < 4; j++)
            b[j] = *(const bf16x8*)(Bs + (wc + j * 16 + lane15) * 32 + quad * 8);
#pragma unroll
        for (int i = 0; i < 4; i++)
#pragma unroll
            for (int j = 0; j < 4; j++)
                acc[i][j] = __builtin_amdgcn_mfma_f32_16x16x32_bf16(a[i], b[j], acc[i][j], 0, 0, 0);
    }

#pragma unroll
    for (int i = 0; i < 4; i++)
#pragma unroll
        for (int j = 0; j < 4; j++)
#pragma unroll
            for (int r = 0; r < 4; r++) {
                const size_t gm = rowBlock + wr + i * 16 + quad * 4 + r;
                const size_t gn = colBlock + wc + j * 16 + lane15;
                if (OUT_F32)
                    ((float*)Cout)[gm * Nd + gn] = acc[i][j][r];
                else
                    ((__bf16*)Cout)[gm * Nd + gn] = (__bf16)acc[i][j][r];
            }
}

// ---------------------------------------------------------------------------
// RoPE in place on (B*T, 4096) bf16, vectorized: 8 elems (4 pairs) / thread.
// grid.y: 0 -> Q buffer, 1 -> K buffer.
// ---------------------------------------------------------------------------
__global__ __launch_bounds__(256) void rope2_inplace(__bf16* __restrict__ Q,
                                                     __bf16* __restrict__ K) {
    __bf16* X = blockIdx.y == 0 ? Q : K;
    const size_t id = (size_t)blockIdx.x * blockDim.x + threadIdx.x;  // one per 8 elems
    const int g = (int)(id & 511);          // 8-elem group within row (4096/8)
    const size_t row = id >> 9;             // 0..4095
    const int tpos = (int)(row & (TSEQ - 1));
    __bf16* p = X + row * DM + (size_t)g * 8;
    bf16x8 v = *(const bf16x8*)p;
    bf16x8 o;
#pragma unroll
    for (int pr = 0; pr < 4; pr++) {
        const int pcol = g * 4 + pr;            // pair index within row, 0..2047
        const int j = (2 * (pcol & 63)) & 63;   // freq index
        // log2(20000) = 14.287712379549449
        const float inv = exp2f(-(float)j * (14.287712379549449f / 64.0f));
        const float ang = (float)tpos * inv;
        float s, c;
        sincosf(ang, &s, &c);
        const float x0 = (float)v[2 * pr], x1 = (float)v[2 * pr + 1];
        o[2 * pr]     = (__bf16)(x0 * c - x1 * s);
        o[2 * pr + 1] = (__bf16)(x0 * s + x1 * c);
    }
    *(bf16x8*)p = o;
}

// ---------------------------------------------------------------------------
// Flash attention, causal. Q,K,V,O all (B*T, 4096) bf16 with head offset h*128.
// Block: 256 thr (4 waves). Q tile 64 rows (16/wave), K/V tiles of 64 keys.
// R3 structure (swapped QK^T):
//   s[n] = mfma(A=K-frag, B=Q-frag): lane (quad,l15) holds
//   S[qrow=w*16+l15][key = n*16 + quad*4 + r].  Softmax per-lane scalar
//   (m_i,l_i for row l15); cross-quad reduce via shfl_xor 16/32.
//   P packed bf16x2 -> Ps[64][64] XOR-swizzled; PV A-frag read intra-wave.
// LDS (40KB, 4 blocks/CU), all conflict-clean:
//   Ks[key][dim]  64x128, 256B rows, 16B slot s at s ^ (key&7)  (gload_lds)
//   Vt[dim][key] 128x64, 128B rows, byte ^ ((dim&7)<<4)
//   Ps[row][key]  64x64, 128B rows, byte ^ ((row&7)<<4)
// ---------------------------------------------------------------------------
__global__ __launch_bounds__(256) void flash_attn(const __bf16* __restrict__ Qg,
                                                  const __bf16* __restrict__ Kg,
                                                  const __bf16* __restrict__ Vg,
                                                  __bf16* __restrict__ Og) {
    const int qb = 31 - blockIdx.x;      // heavy-first
    const int bh = blockIdx.y;           // 0..63
    const int b = bh >> 5, h = bh & 31;
    const size_t base = (size_t)b * TSEQ * DM + (size_t)h * DH;
    const __bf16* Qp = Qg + base;
    const __bf16* Kp = Kg + base;
    const __bf16* Vp = Vg + base;
    __bf16*       Op = Og + base;

    __shared__ alignas(16) __bf16 Ks[64 * 128];
    __shared__ alignas(16) __bf16 Vt[128 * 64];
    __shared__ alignas(16) __bf16 Ps[64 * 64];

    const int t = threadIdx.x, w = t >> 6, L = t & 63;
    const int lane15 = L & 15, quad = L >> 4;
    const int sw = (lane15 & 7) << 4;    // read-side XOR (row&7 == lane15&7)
    const int rowPs = w * 16 + lane15;   // this lane's P row (q-row, wave-rel l15)

    // Q B-frags (n = q-row = lane15): same data layout as an A-frag load.
    bf16x8 bq[4];
    const int qrow = qb * 64 + w * 16 + lane15;   // global q-row of this lane's P row
#pragma unroll
    for (int ks = 0; ks < 4; ++ks)
        bq[ks] = *(const bf16x8*)(Qp + (size_t)qrow * DM + ks * 32 + quad * 8);

    f32x4 o[8] = {};
    float m_i = -1e30f, l_i = 0.0f;
    const float scale = 0.08838834764831845f;  // 1/sqrt(128)

    for (int kt = 0; kt <= qb; ++kt) {
        if (kt) __syncthreads();         // all waves done reading Ks/Vt of prev tile

        // ---- stage V -> regs (lane = key, wave strides dim blocks) ----
        bf16x8 vv[4];
#pragma unroll
        for (int c = 0; c < 4; c++) {
            const int d0 = (c * 4 + w) * 8;
            vv[c] = *(const bf16x8*)(Vp + (size_t)(kt * 64 + L) * DM + d0);
        }
        // ---- stage K via global_load_lds, source pre-swizzled ----
#pragma unroll
        for (int c = 0; c < 4; c++) {
            const int chunk0 = c * 256 + (w << 6);                // wave-uniform
            const int chunk  = chunk0 + L;
            const int row = chunk >> 4;                           // key 0..63
            const int ssw = (chunk & 15) ^ (row & 7);             // swizzled source slot
            __builtin_amdgcn_global_load_lds(
                GLD_A1(Kp + (size_t)(kt * 64 + row) * DM + ssw * 8),
                GLD_A3((char*)Ks + chunk0 * 16), 16, 0, 0);
        }
        // ---- transposed V writes: contiguous across 64 lanes, uniform XOR ----
#pragma unroll
        for (int c = 0; c < 4; c++) {
            const int d0 = (c * 4 + w) * 8;
#pragma unroll
            for (int jj = 0; jj < 8; jj++)
                *(__bf16*)((char*)Vt + (d0 + jj) * 128 + ((L * 2) ^ (jj << 4))) = vv[c][jj];
        }
        __syncthreads();  // drains vmcnt+lgkm: Ks, Vt populated

        // ---- S^T = K Q^T : lane holds S[qrow=l15][key = n*16+quad*4+r] ----
        f32x4 s[4] = {};
        __builtin_amdgcn_s_setprio(1);
#pragma unroll
        for (int ks = 0; ks < 4; ++ks)
#pragma unroll
            for (int n = 0; n < 4; n++) {
                bf16x8 ak = *(const bf16x8*)((const char*)Ks + (n * 16 + lane15) * 256
                                             + ((ks * 64 + quad * 16) ^ sw));
                s[n] = __builtin_amdgcn_mfma_f32_16x16x32_bf16(ak, bq[ks], s[n], 0, 0, 0);
            }
        __builtin_amdgcn_s_setprio(0);

        // ---- scale + causal mask (per-lane, keys n*16+quad*4+r) ----
        const bool diag = (kt == qb);
#pragma unroll
        for (int n = 0; n < 4; n++)
#pragma unroll
            for (int r = 0; r < 4; r++) {
                const int col = kt * 64 + n * 16 + quad * 4 + r;
                float sv = s[n][r] * scale;
                if (diag && col > qrow) sv = -1e30f;
                s[n][r] = sv;
            }

        // ---- online softmax: row is lane-local, reduce across quads only ----
        float mx = s[0][0];
#pragma unroll
        for (int n = 0; n < 4; n++)
#pragma unroll
            for (int r = 0; r < 4; r++) mx = fmaxf(mx, s[n][r]);
        mx = fmaxf(mx, __shfl_xor(mx, 16));
        mx = fmaxf(mx, __shfl_xor(mx, 32));
        const float mn = fmaxf(m_i, mx);
        const float al = __expf(m_i - mn);
        m_i = mn;

        float p[4][4];
        float rs = 0.0f;
#pragma unroll
        for (int n = 0; n < 4; n++)
#pragma unroll
            for (int r = 0; r < 4; r++) {
                p[n][r] = __expf(s[n][r] - mn);
                rs += p[n][r];
            }
        rs += __shfl_xor(rs, 16);
        rs += __shfl_xor(rs, 32);
        l_i = l_i * al + rs;

        // ---- write P pairs (bf16x2) to swizzled Ps; intra-wave round trip ----
#pragma unroll
        for (int n = 0; n < 4; n++)
#pragma unroll
            for (int hh = 0; hh < 2; hh++) {
                bf16x2 pr = { (__bf16)p[n][2 * hh], (__bf16)p[n][2 * hh + 1] };
                const int byte = rowPs * 128 + ((n * 32 + quad * 8 + hh * 4) ^ sw);
                *(bf16x2*)((char*)Ps + byte) = pr;
            }

        // ---- rescale O (factors redistributed: o rows are q-rows quad*4+r) ----
        float alr[4];
#pragma unroll
        for (int r = 0; r < 4; r++) alr[r] = __shfl(al, quad * 4 + r);
#pragma unroll
        for (int d = 0; d < 8; ++d)
#pragma unroll
            for (int r = 0; r < 4; r++) o[d][r] *= alr[r];

        // P writes visible to own wave's cross-lane reads (no barrier needed).
        asm volatile("s_waitcnt lgkmcnt(0)" ::: "memory");
        __builtin_amdgcn_sched_barrier(0);

        // ---- O += P V ----
        __builtin_amdgcn_s_setprio(1);
#pragma unroll
        for (int ks2 = 0; ks2 < 2; ++ks2) {
            bf16x8 ap = *(const bf16x8*)((const char*)Ps + rowPs * 128
                                         + ((ks2 * 64 + quad * 16) ^ sw));
#pragma unroll
            for (int d = 0; d < 8; ++d) {
                bf16x8 bv = *(const bf16x8*)((const char*)Vt + (d * 16 + lane15) * 128
                                             + ((ks2 * 64 + quad * 16) ^ sw));
                o[d] = __builtin_amdgcn_mfma_f32_16x16x32_bf16(ap, bv, o[d], 0, 0, 0);
            }
        }
        __builtin_amdgcn_s_setprio(0);
    }

    // ---- epilogue: O / l (l redistributed like al) ----
    float lr[4];
#pragma unroll
    for (int r = 0; r < 4; r++) lr[r] = 1.0f / __shfl(l_i, quad * 4 + r);
#pragma unroll
    for (int d = 0; d < 8; ++d)
#pragma unroll
        for (int r = 0; r < 4; r++) {
            const int rowq = qb * 64 + w * 16 + quad * 4 + r;
            Op[(size_t)rowq * DM + d * 16 + lane15] = (__bf16)(o[d][r] * lr[r]);
        }
}

// ---------------------------------------------------------------------------
extern "C" void kernel_launch(void* const* d_in, const int* in_sizes, int n_in,
                              void* d_out, int out_size, void* d_ws, size_t ws_size,
                              hipStream_t stream) {
    const float* hs = (const float*)d_in[0];
    const float* Wq = (const float*)d_in[1];
    const float* Wk = (const float*)d_in[2];
    const float* Wv = (const float*)d_in[3];
    const float* Wo = (const float*)d_in[4];
    float* out = (float*)d_out;

    // workspace layout: 9 bf16 buffers of TS elems (~302 MB total)
    __bf16* hs_b = (__bf16*)d_ws;
    __bf16* wq_b = hs_b + TS;
    __bf16* wk_b = wq_b + TS;
    __bf16* wv_b = wk_b + TS;
    __bf16* wo_b = wv_b + TS;
    __bf16* Qb   = wo_b + TS;
    __bf16* Kb   = Qb + TS;
    __bf16* Vb   = Kb + TS;
    __bf16* Ab   = Vb + TS;
    if (ws_size < 9 * TS * sizeof(__bf16)) return;  // insufficient scratch

    const dim3 blk(256);
    // merged cast: grid.y picks source; dests are contiguous from hs_b
    cast5_f32_bf16<<<dim3(TS / 4 / 256, 5), blk, 0, stream>>>(hs, Wq, Wk, Wv, Wo, hs_b);

    const dim3 ggrid(32, 32);  // (N/128, M/128)
    gemm_nt<false><<<ggrid, blk, 0, stream>>>(hs_b, wq_b, (void*)Qb);
    gemm_nt<false><<<ggrid, blk, 0, stream>>>(hs_b, wk_b, (void*)Kb);
    gemm_nt<false><<<ggrid, blk, 0, stream>>>(hs_b, wv_b, (void*)Vb);

    rope2_inplace<<<dim3(TS / 8 / 256, 2), blk, 0, stream>>>(Qb, Kb);

    flash_attn<<<dim3(32, 64), blk, 0, stream>>>(Qb, Kb, Vb, Ab);

    gemm_nt<true><<<ggrid, blk, 0, stream>>>(Ab, wo_b, (void*)out);
}